// Round 14
// baseline (21392.015 us; speedup 1.0000x reference)
//
#include <hip/hip_runtime.h>
#include <hip/hip_bf16.h>

#define Bb 128
#define Tt 512
#define Dd 1024
#define Hh 1024
#define KD 2048
#define CCH 32               // time steps per Zx chunk == h-ring depth
#define NCHUNK (Tt / CCH)    // 16
#define NBLK 256             // recurrence blocks
#define NZXB 256             // zx-producer blocks (fused mode)

typedef __attribute__((ext_vector_type(4))) float f32x4;
typedef __attribute__((ext_vector_type(8))) short s16x8;
typedef __attribute__((address_space(1))) const void gcvoid;
typedef __attribute__((address_space(3))) void lvoid;

__device__ __forceinline__ unsigned short f2bf(float f) {
    union { float f; unsigned u; } v;
    v.f = f;
    unsigned r = v.u + 0x7fffu + ((v.u >> 16) & 1u);
    return (unsigned short)(r >> 16);
}

__device__ __forceinline__ s16x8 cvt8(const float* src) {
    f32x4 a = *reinterpret_cast<const f32x4*>(src);
    f32x4 b = *reinterpret_cast<const f32x4*>(src + 4);
    s16x8 v;
    v[0] = (short)f2bf(a[0]); v[1] = (short)f2bf(a[1]);
    v[2] = (short)f2bf(a[2]); v[3] = (short)f2bf(a[3]);
    v[4] = (short)f2bf(b[0]); v[5] = (short)f2bf(b[1]);
    v[6] = (short)f2bf(b[2]); v[7] = (short)f2bf(b[3]);
    return v;
}

__device__ __forceinline__ float sigf(float x)      { return 1.f / (1.f + __expf(-x)); }
__device__ __forceinline__ float tanhfast(float x)  { return 1.f - 2.f / (1.f + __expf(2.f * x)); }

// sc1 = device-coherent (LLC write-through) store: release side of h hand-off.
__device__ __forceinline__ void cstore2(unsigned short* p, unsigned v) {
    asm volatile("global_store_short %0, %1, off sc1" :: "v"(p), "v"(v) : "memory");
}

// R12-proven all-relaxed two-level barrier among the NBLK recurrence blocks.
__device__ __forceinline__ void gbar(unsigned* cntA, unsigned* cntB,
                                     unsigned* flag, int t, int bid) {
    asm volatile("s_waitcnt vmcnt(0)" ::: "memory");   // sc1 h-stores ack'd (per wave)
    __syncthreads();
    if (threadIdx.x == 0) {
        unsigned* ca = cntA + ((size_t)t * 8 + (bid & 7)) * 32;
        unsigned o = __hip_atomic_fetch_add(ca, 1u, __ATOMIC_RELAXED, __HIP_MEMORY_SCOPE_AGENT);
        if (o == 31u) {
            unsigned* cb = cntB + (size_t)t * 32;
            unsigned o2 = __hip_atomic_fetch_add(cb, 1u, __ATOMIC_RELAXED, __HIP_MEMORY_SCOPE_AGENT);
            if (o2 == 7u)
                __hip_atomic_store(flag + t, 1u, __ATOMIC_RELAXED, __HIP_MEMORY_SCOPE_AGENT);
        }
        while (__hip_atomic_load(flag + t, __ATOMIC_RELAXED, __HIP_MEMORY_SCOPE_AGENT) == 0u)
            __builtin_amdgcn_s_sleep(1);
    }
    __syncthreads();
}

// ---------------------------------------------------------------------------
// Shared zx tile body: one 128x128 output tile at (m0, n0) of the chunk GEMM
// M=4096 (B*CCH), N=4096, K=1024. smem = 64 KB (A 2x16KB | B 2x16KB).
// ---------------------------------------------------------------------------
__device__ __forceinline__ void zx_tile(
    const float* __restrict__ X, const unsigned short* __restrict__ Wr,
    const float* __restrict__ bre, float* __restrict__ Zxc,
    int t0, int m0, int n0, unsigned char* smem)
{
    unsigned short* ALds = (unsigned short*)smem;             // [2][8192]
    unsigned short* BLds = (unsigned short*)(smem + 32768);   // [2][8192]

    const int tid = threadIdx.x, lane = tid & 63, wv = tid >> 6;
    const int wr = wv >> 1, wc = wv & 1;

    f32x4 acc[4][4];
#pragma unroll
    for (int i = 0; i < 4; ++i)
#pragma unroll
        for (int jn = 0; jn < 4; ++jn) acc[i][jn] = 0.f;

    auto stage = [&](int buf, int ki) {
        const int k0 = ki * 64;
#pragma unroll
        for (int i = 0; i < 4; ++i) {
            int slot = i * 256 + tid;
            int r = slot >> 3, cp = slot & 7;
            int c = cp ^ (r & 7);
            int m = m0 + r, b = m >> 5, tc = m & 31;
            const float* src = X + ((size_t)b * Tt + t0 + tc) * Dd + k0 + c * 8;
            *reinterpret_cast<s16x8*>(&ALds[buf * 8192 + slot * 8]) = cvt8(src);
        }
#pragma unroll
        for (int i = 0; i < 4; ++i) {
            int slot = i * 256 + tid;
            int r = slot >> 3, cp = slot & 7;
            int c = cp ^ (r & 7);
            const unsigned short* src = Wr + (size_t)(n0 + r) * KD + k0 + c * 8;
            __builtin_amdgcn_global_load_lds((gcvoid*)src,
                (lvoid*)&BLds[buf * 8192 + (i * 256 + wv * 64) * 8], 16, 0, 0);
        }
    };

    auto compute = [&](int buf) {
#pragma unroll
        for (int ks = 0; ks < 2; ++ks) {
            int ck = ks * 4 + (lane >> 4);
            s16x8 af[4], bf8[4];
#pragma unroll
            for (int m = 0; m < 4; ++m) {
                int ra = wr * 64 + m * 16 + (lane & 15);
                af[m] = *reinterpret_cast<const s16x8*>(&ALds[buf * 8192 + ra * 64 + (ck ^ (ra & 7)) * 8]);
            }
#pragma unroll
            for (int n = 0; n < 4; ++n) {
                int rb = wc * 64 + n * 16 + (lane & 15);
                bf8[n] = *reinterpret_cast<const s16x8*>(&BLds[buf * 8192 + rb * 64 + (ck ^ (rb & 7)) * 8]);
            }
#pragma unroll
            for (int m = 0; m < 4; ++m)
#pragma unroll
                for (int n = 0; n < 4; ++n)
                    acc[m][n] = __builtin_amdgcn_mfma_f32_16x16x32_bf16(af[m], bf8[n], acc[m][n], 0, 0, 0);
        }
    };

    stage(0, 0);
#pragma unroll 1
    for (int ki = 0; ki < 16; ++ki) {
        __syncthreads();   // drains vmcnt/lgkmcnt for staging visibility
        if (ki + 1 < 16) stage((ki + 1) & 1, ki + 1);
        compute(ki & 1);
    }

#pragma unroll
    for (int ni = 0; ni < 4; ++ni) {
        int gcol = n0 + wc * 64 + ni * 16 + (lane & 15);
        float bias = bre[gcol];
        int gg = gcol >> 5, nn = gcol & 31;
        int zcol = gg * 32 + (nn & 7) * 4 + (nn >> 3);
#pragma unroll
        for (int mi = 0; mi < 4; ++mi) {
            int rbase = m0 + wr * 64 + mi * 16 + (lane >> 4) * 4;
#pragma unroll
            for (int r = 0; r < 4; ++r)
                Zxc[(size_t)(rbase + r) * 4096 + zcol] = acc[mi][ni][r] + bias;
        }
    }
}

// Standalone zx kernel (prologue + non-fused mode): 1024 blocks, 1 tile each.
__global__ __launch_bounds__(256) void zx_gemm(
    const float* __restrict__ X, const unsigned short* __restrict__ Wr,
    const float* __restrict__ bre, float* __restrict__ Zxc, int t0)
{
    __shared__ __align__(16) unsigned char smem[65536];
    const int tile = blockIdx.x;
    zx_tile(X, Wr, bre, Zxc, t0, (tile >> 5) * 128, (tile & 31) * 128, smem);
}

// ---------------------------------------------------------------------------
// Fused persistent kernel. Blocks [0,256): recurrence chunk t0 (R12 verbatim,
// reads ZxcRead). Blocks [256,512): producer role — compute Zx for chunk
// t0z = t0+CCH into ZxcWrite (4 tiles each); consumed by the NEXT launch
// (kernel-boundary coherence). No inter-role sync, no deadlock possibility.
// ---------------------------------------------------------------------------
__global__ __launch_bounds__(256) void lstm_chunk(
    const float* __restrict__ X,
    const unsigned short* __restrict__ Wr,
    const float* __restrict__ ZxcRead,
    float* __restrict__ ZxcWrite,
    const float* __restrict__ bre,
    unsigned short* __restrict__ hring,   // CCH slots of [Bb][Hh] bf16
    float* __restrict__ cbuf,
    float* __restrict__ out,
    unsigned* __restrict__ cntA,
    unsigned* __restrict__ cntB,
    unsigned* __restrict__ flag,
    int t0, int t0z)
{
    __shared__ __align__(16) unsigned char smem[65536];

    const int bid = blockIdx.x;

    if (bid >= NBLK) {                    // ---- zx producer role ----
        if (t0z < Tt) {
            const int zbid = bid - NBLK;
#pragma unroll 1
            for (int q = 0; q < 4; ++q) {
                int tile = zbid + NZXB * q;
                zx_tile(X, Wr, bre, ZxcWrite, t0z,
                        (tile >> 5) * 128, (tile & 31) * 128, smem);
                __syncthreads();
            }
        }
        return;
    }

    // ---- recurrence role (R12 verbatim) ----
    unsigned short* Bl = (unsigned short*)smem;               // 64 KB Wh slice

    const int tid = threadIdx.x, lane = tid & 63, w = tid >> 6;
    const int g = bid >> 1, mh = bid & 1;

#pragma unroll
    for (int i = 0; i < 16; ++i) {
        int q = (w * 16 + i) * 64 + lane;
        int n = q >> 7, cp = q & 127;
        int cs = (cp & ~7) | ((cp ^ n) & 7);
        const unsigned short* src = Wr + (size_t)(g * 32 + n) * KD + Dd + cs * 8;
        __builtin_amdgcn_global_load_lds((gcvoid*)src,
            (lvoid*)&Bl[(w * 16 + i) * 512], 16, 0, 0);
    }
    asm volatile("s_waitcnt vmcnt(0)" ::: "memory");
    __syncthreads();

    const int nlo = lane & 15;
    const int r0 = mh * 64 + w * 16 + nlo;
    const unsigned short* b0p = &Bl[nlo * 1024];
    const int jj = lane & 7, j = g * 8 + jj;
    const bool hi = (lane & 8) != 0;
    const int rowb = mh * 64 + w * 16 + (lane >> 4) * 4;

    f32x4 creg;
#pragma unroll
    for (int r = 0; r < 4; ++r)
        creg[r] = cbuf[(size_t)(rowb + r) * Hh + j];

    f32x4 zx[4];
#pragma unroll
    for (int r = 0; r < 4; ++r)
        zx[r] = *reinterpret_cast<const f32x4*>(
            ZxcRead + ((size_t)(rowb + r) * CCH + 0) * 4096 + j * 4);

#pragma unroll 1
    for (int tt = 0; tt < CCH; ++tt) {
        const int t = t0 + tt;
        const unsigned short* hin = hring + (size_t)(t & (CCH - 1)) * (Bb * Hh);
        unsigned short* houtp = hring + (size_t)((t + 1) & (CCH - 1)) * (Bb * Hh);
        const unsigned short* arow = hin + (size_t)r0 * Hh + (lane >> 4) * 8;

        s16x8 af[32];
#pragma unroll
        for (int ki = 0; ki < 32; ++ki)
            af[ki] = *reinterpret_cast<const s16x8*>(arow + ki * 32);

        f32x4 acc0 = 0.f, acc1 = 0.f;
#pragma unroll
        for (int ki = 0; ki < 32; ++ki) {
            int ck = ki * 4 + (lane >> 4);
            int p = (ck & ~7) | ((ck ^ nlo) & 7);
            s16x8 b0 = *reinterpret_cast<const s16x8*>(b0p + p * 8);
            s16x8 b1 = *reinterpret_cast<const s16x8*>(b0p + 16 * 1024 + p * 8);
            acc0 = __builtin_amdgcn_mfma_f32_16x16x32_bf16(af[ki], b0, acc0, 0, 0, 0);
            acc1 = __builtin_amdgcn_mfma_f32_16x16x32_bf16(af[ki], b1, acc1, 0, 0, 0);
        }

        f32x4 y0, y1;
#pragma unroll
        for (int r = 0; r < 4; ++r) {
            y0[r] = __shfl_xor(acc0[r], 8, 64);
            y1[r] = __shfl_xor(acc1[r], 8, 64);
        }

        f32x4 zxn[4];
        if (tt + 1 < CCH) {
#pragma unroll
            for (int r = 0; r < 4; ++r)
                zxn[r] = *reinterpret_cast<const f32x4*>(
                    ZxcRead + ((size_t)(rowb + r) * CCH + (tt + 1)) * 4096 + j * 4);
        }

#pragma unroll
        for (int r = 0; r < 4; ++r) {
            float vf = hi ? y0[r] : acc0[r];
            float vi = hi ? acc0[r] : y0[r];
            float vo = hi ? y1[r] : acc1[r];
            float vg = hi ? acc1[r] : y1[r];
            float zf = vf + zx[r][0], zi = vi + zx[r][1];
            float zo = vo + zx[r][2], zc = vg + zx[r][3];
            float fg = sigf(zf), ig = sigf(zi), og = sigf(zo), gv = tanhfast(zc);
            float cnew = fg * creg[r] + ig * gv;
            creg[r] = cnew;
            float hn = og * tanhfast(cnew);
            if (!hi) {
                int row = rowb + r;
                cstore2(houtp + (size_t)row * Hh + j, (unsigned)f2bf(hn));
                out[((size_t)row * Tt + (Tt - 1 - t)) * Hh + j] = hn;
            }
        }
#pragma unroll
        for (int r = 0; r < 4; ++r) zx[r] = zxn[r];

        if (tt + 1 < CCH) gbar(cntA, cntB, flag, t, bid);
    }

    if (!hi) {
#pragma unroll
        for (int r = 0; r < 4; ++r)
            cbuf[(size_t)(rowb + r) * Hh + j] = creg[r];
    }
}

// ---------------------------------------------------------------------------
// Weight reorg as LDS-tiled transpose: Wr[n][k] = bf16(Wg[k][col(n)]),
// n = (col>>3)*32 + gate*8 + (col&7).
// ---------------------------------------------------------------------------
__global__ __launch_bounds__(256) void conv_w(
    const float* __restrict__ Wf, const float* __restrict__ Wi,
    const float* __restrict__ Wo, const float* __restrict__ Wc,
    unsigned short* __restrict__ Wr)
{
    __shared__ float sm[64 * 65];
    const int tid = threadIdx.x;
    const int bid = blockIdx.x;
    const int gate = bid & 3;
    const int rest = bid >> 2;
    const int k0 = (rest & 31) * 64;
    const int c0 = (rest >> 5) * 64;
    const float* Wg = (gate == 0) ? Wf : (gate == 1) ? Wi : (gate == 2) ? Wo : Wc;

#pragma unroll
    for (int it = 0; it < 16; ++it) {
        int kl = it * 4 + (tid >> 6), cl = tid & 63;
        sm[kl * 65 + cl] = Wg[(size_t)(k0 + kl) * Hh + c0 + cl];
    }
    __syncthreads();
#pragma unroll
    for (int it = 0; it < 16; ++it) {
        int nl = it * 4 + (tid >> 6), kl = tid & 63;
        int col = c0 + nl;
        int n = (col >> 3) * 32 + gate * 8 + (col & 7);
        Wr[(size_t)n * KD + k0 + kl] = f2bf(sm[kl * 65 + nl]);
    }
}

#define NBAR_U32 (512 * 8 * 32 + 512 * 32 + 512)

__global__ void init_all(unsigned short* __restrict__ hring, float* __restrict__ cbuf,
                         unsigned* __restrict__ bars, float* __restrict__ bre,
                         const float* __restrict__ bF, const float* __restrict__ bI,
                         const float* __restrict__ bO, const float* __restrict__ bC) {
    int i = blockIdx.x * 256 + threadIdx.x;
    if (i < 2 * Bb * Hh) hring[i] = 0;   // slots 0 (t=0 carry) and 1 (fallback)
    if (i < Bb * Hh) cbuf[i] = 0.f;
    if (i < NBAR_U32) bars[i] = 0u;
    if (i < 4096) {
        int gate = (i >> 3) & 3, g = i >> 5, jjv = i & 7;
        int col = g * 8 + jjv;
        const float* bg = (gate == 0) ? bF : (gate == 1) ? bI : (gate == 2) ? bO : bC;
        bre[i] = bg[col];
    }
}

// ---------------------------------------------------------------------------
// Fallback path: one fused kernel per time step, K=2048 (round-1/3 proven).
// ---------------------------------------------------------------------------
__global__ __launch_bounds__(256) void lstm_step(
    const float* __restrict__ X, const unsigned short* __restrict__ Wr,
    const float* __restrict__ bre,
    const unsigned short* __restrict__ hin, unsigned short* __restrict__ hout,
    float* __restrict__ cbuf, float* __restrict__ out, int t)
{
    __shared__ __align__(16) unsigned short Alds[2][64 * 64];
    __shared__ __align__(16) unsigned short Blds[2][32 * 64];
    __shared__ float zlds[64 * 33];

    const int tid = threadIdx.x, lane = tid & 63, w = tid >> 6;
    const int g = blockIdx.x >> 1, mh = blockIdx.x & 1;

    f32x4 acc[2];
    acc[0] = 0.f; acc[1] = 0.f;

    auto stageA = [&](int buf, int ki) {
        const int k0 = ki * 64;
#pragma unroll
        for (int i = 0; i < 2; ++i) {
            int slot = tid + 256 * i;
            int r = slot >> 3, cp = slot & 7;
            int c = cp ^ (r & 7);
            int k = k0 + c * 8;
            s16x8 v;
            if (k < Dd) {
                v = cvt8(X + ((size_t)(mh * 64 + r) * Tt + t) * Dd + k);
            } else {
                v = *reinterpret_cast<const s16x8*>(hin + (size_t)(mh * 64 + r) * Hh + (k - Dd));
            }
            *reinterpret_cast<s16x8*>(&Alds[buf][slot * 8]) = v;
        }
    };
    auto stageB = [&](int buf, int ki) {
        int n = tid >> 3, cp = tid & 7;
        int c = cp ^ (n & 7);
        const unsigned short* src = Wr + (size_t)(g * 32 + n) * KD + ki * 64 + c * 8;
        *reinterpret_cast<s16x8*>(&Blds[buf][tid * 8]) = *reinterpret_cast<const s16x8*>(src);
    };
    auto compute = [&](int buf) {
#pragma unroll
        for (int ks = 0; ks < 2; ++ks) {
            int ra = w * 16 + (lane & 15);
            int cha = (ks * 4 + (lane >> 4)) ^ (ra & 7);
            s16x8 af = *reinterpret_cast<const s16x8*>(&Alds[buf][ra * 64 + cha * 8]);
#pragma unroll
            for (int nt = 0; nt < 2; ++nt) {
                int n = nt * 16 + (lane & 15);
                int chb = (ks * 4 + (lane >> 4)) ^ (n & 7);
                s16x8 bf8 = *reinterpret_cast<const s16x8*>(&Blds[buf][n * 64 + chb * 8]);
                acc[nt] = __builtin_amdgcn_mfma_f32_16x16x32_bf16(af, bf8, acc[nt], 0, 0, 0);
            }
        }
    };

    stageA(0, 0); stageB(0, 0);
#pragma unroll 1
    for (int ki = 0; ki < 32; ++ki) {
        __syncthreads();
        if (ki + 1 < 32) { stageA((ki + 1) & 1, ki + 1); stageB((ki + 1) & 1, ki + 1); }
        compute(ki & 1);
    }

    {
        int rbase = w * 16 + (lane >> 4) * 4;
#pragma unroll
        for (int nt = 0; nt < 2; ++nt) {
            int col = nt * 16 + (lane & 15);
#pragma unroll
            for (int r = 0; r < 4; ++r)
                zlds[(rbase + r) * 33 + col] = acc[nt][r];
        }
    }
    __syncthreads();

#pragma unroll
    for (int it = 0; it < 2; ++it) {
        int idx = tid + it * 256;
        int row = idx >> 3, jj = idx & 7;
        int jx = g * 8 + jj;
        int grow = mh * 64 + row;
        float zf = zlds[row * 33 + jj]      + bre[g * 32 + jj];
        float zi = zlds[row * 33 + 8 + jj]  + bre[g * 32 + 8 + jj];
        float zo = zlds[row * 33 + 16 + jj] + bre[g * 32 + 16 + jj];
        float zc = zlds[row * 33 + 24 + jj] + bre[g * 32 + 24 + jj];
        float fg = sigf(zf), ig = sigf(zi), og = sigf(zo), gv = tanhfast(zc);
        float cold = cbuf[(size_t)grow * Hh + jx];
        float cnew = fg * cold + ig * gv;
        cbuf[(size_t)grow * Hh + jx] = cnew;
        float hn = og * tanhfast(cnew);
        hout[(size_t)grow * Hh + jx] = f2bf(hn);
        out[((size_t)grow * Tt + (Tt - 1 - t)) * Hh + jx] = hn;
    }
}

extern "C" void kernel_launch(void* const* d_in, const int* in_sizes, int n_in,
                              void* d_out, int out_size, void* d_ws, size_t ws_size,
                              hipStream_t stream) {
    (void)in_sizes; (void)n_in; (void)out_size;
    const float* X  = (const float*)d_in[0];
    const float* Wf = (const float*)d_in[1];
    const float* bF = (const float*)d_in[2];
    const float* Wi = (const float*)d_in[3];
    const float* bI = (const float*)d_in[4];
    const float* Wo = (const float*)d_in[5];
    const float* bO = (const float*)d_in[6];
    const float* Wc = (const float*)d_in[7];
    const float* bC = (const float*)d_in[8];
    float* out = (float*)d_out;

    char* ws = (char*)d_ws;
    size_t off = 0;
    auto carve = [&](size_t sz) { char* p = ws + off; off = (off + sz + 255) & ~(size_t)255; return p; };
    unsigned short* Wr    = (unsigned short*)carve((size_t)4096 * KD * 2);        // 16 MB
    float*          bre   = (float*)carve(4096 * 4);
    unsigned short* hring = (unsigned short*)carve((size_t)CCH * Bb * Hh * 2);    // 8 MB
    float*          cbuf  = (float*)carve((size_t)Bb * Hh * 4);
    unsigned*       bars  = (unsigned*)carve((size_t)NBAR_U32 * 4);               // ~0.6 MB
    float*          Zxc0  = (float*)carve((size_t)4096 * 4096 * 4);               // 64 MB
    const size_t need_r12 = off;
    float*          Zxc1  = (float*)carve((size_t)4096 * 4096 * 4);               // 64 MB
    const size_t need_big = off;

    unsigned* cntA = bars;
    unsigned* cntB = bars + 512 * 8 * 32;
    unsigned* flag = bars + 512 * 8 * 32 + 512 * 32;

    conv_w<<<2048, 256, 0, stream>>>(Wf, Wi, Wo, Wc, Wr);
    init_all<<<1024, 256, 0, stream>>>(hring, cbuf, bars, bre, bF, bI, bO, bC);

    const bool fused = (ws_size >= need_big);
    const bool r12ok = (ws_size >= need_r12);

    int t_resume = 0;                 // first timestep NOT handled by coop path
    if (fused) {
        zx_gemm<<<1024, 256, 0, stream>>>(X, Wr, bre, Zxc0, 0);     // prologue: Zx(chunk 0)
        for (int c = 0; c < NCHUNK; ++c) {
            int t0 = c * CCH;
            int t0z = t0 + CCH;                                      // next chunk's Zx
            const float* zrd = (c & 1) ? Zxc1 : Zxc0;
            float*       zwr = (c & 1) ? Zxc0 : Zxc1;
            void* args[] = {(void*)&X, (void*)&Wr, (void*)&zrd, (void*)&zwr, (void*)&bre,
                            (void*)&hring, (void*)&cbuf, (void*)&out,
                            (void*)&cntA, (void*)&cntB, (void*)&flag,
                            (void*)&t0, (void*)&t0z};
            hipError_t rc = hipLaunchCooperativeKernel((void*)lstm_chunk,
                                                       dim3(NBLK + NZXB), dim3(256),
                                                       args, 0, stream);
            if (rc != hipSuccess) break;
            t_resume = t0 + CCH;
        }
    } else if (r12ok) {
        for (int c = 0; c < NCHUNK; ++c) {
            int t0 = c * CCH;
            int t0z = Tt;                                            // producer role disabled
            const float* zrd = Zxc0;
            float*       zwr = Zxc0;
            zx_gemm<<<1024, 256, 0, stream>>>(X, Wr, bre, Zxc0, t0);
            void* args[] = {(void*)&X, (void*)&Wr, (void*)&zrd, (void*)&zwr, (void*)&bre,
                            (void*)&hring, (void*)&cbuf, (void*)&out,
                            (void*)&cntA, (void*)&cntB, (void*)&flag,
                            (void*)&t0, (void*)&t0z};
            hipError_t rc = hipLaunchCooperativeKernel((void*)lstm_chunk,
                                                       dim3(NBLK), dim3(256),
                                                       args, 0, stream);
            if (rc != hipSuccess) break;
            t_resume = t0 + CCH;
        }
    }

    // Per-step proven path for anything the coop path didn't cover.
    // (h state at t_resume sits in ring slot 0 == slot (t_resume & 1).)
    for (int t = t_resume; t < Tt; ++t) {
        const unsigned short* hin = hring + (size_t)(t & 1) * Bb * Hh;
        unsigned short*      houtp = hring + (size_t)((t + 1) & 1) * Bb * Hh;
        lstm_step<<<256, 256, 0, stream>>>(X, Wr, bre, hin, houtp, cbuf, out, t);
    }
}

// Round 15
// 5307.715 us; speedup vs baseline: 4.0304x; 4.0304x over previous
//
#include <hip/hip_runtime.h>
#include <hip/hip_bf16.h>

#define Bb 128
#define Tt 512
#define Dd 1024
#define Hh 1024
#define KD 2048
#define CCH 32               // time steps per Zx chunk == h-ring depth
#define NCHUNK (Tt / CCH)    // 16
#define NBLK 256

typedef __attribute__((ext_vector_type(4))) float f32x4;
typedef __attribute__((ext_vector_type(8))) short s16x8;
typedef __attribute__((address_space(1))) const void gcvoid;
typedef __attribute__((address_space(3))) void lvoid;

__device__ __forceinline__ unsigned short f2bf(float f) {
    union { float f; unsigned u; } v;
    v.f = f;
    unsigned r = v.u + 0x7fffu + ((v.u >> 16) & 1u);
    return (unsigned short)(r >> 16);
}

__device__ __forceinline__ s16x8 cvt8(const float* src) {
    f32x4 a = *reinterpret_cast<const f32x4*>(src);
    f32x4 b = *reinterpret_cast<const f32x4*>(src + 4);
    s16x8 v;
    v[0] = (short)f2bf(a[0]); v[1] = (short)f2bf(a[1]);
    v[2] = (short)f2bf(a[2]); v[3] = (short)f2bf(a[3]);
    v[4] = (short)f2bf(b[0]); v[5] = (short)f2bf(b[1]);
    v[6] = (short)f2bf(b[2]); v[7] = (short)f2bf(b[3]);
    return v;
}

__device__ __forceinline__ float sigf(float x)      { return 1.f / (1.f + __expf(-x)); }
__device__ __forceinline__ float tanhfast(float x)  { return 1.f - 2.f / (1.f + __expf(2.f * x)); }

// sc1 = device-coherent (LLC write-through) store: release side of h hand-off.
__device__ __forceinline__ void cstore2(unsigned short* p, unsigned v) {
    asm volatile("global_store_short %0, %1, off sc1" :: "v"(p), "v"(v) : "memory");
}

// R12-proven all-relaxed two-level barrier; caller performs the h-store drain
// (split-drain: vmcnt(4) leaves the 4 non-handoff out-stores in flight).
__device__ __forceinline__ void gbar(unsigned* cntA, unsigned* cntB,
                                     unsigned* flag, int t, int bid) {
    __syncthreads();
    if (threadIdx.x == 0) {
        unsigned* ca = cntA + ((size_t)t * 8 + (bid & 7)) * 32;
        unsigned o = __hip_atomic_fetch_add(ca, 1u, __ATOMIC_RELAXED, __HIP_MEMORY_SCOPE_AGENT);
        if (o == 31u) {
            unsigned* cb = cntB + (size_t)t * 32;
            unsigned o2 = __hip_atomic_fetch_add(cb, 1u, __ATOMIC_RELAXED, __HIP_MEMORY_SCOPE_AGENT);
            if (o2 == 7u)
                __hip_atomic_store(flag + t, 1u, __ATOMIC_RELAXED, __HIP_MEMORY_SCOPE_AGENT);
        }
        while (__hip_atomic_load(flag + t, __ATOMIC_RELAXED, __HIP_MEMORY_SCOPE_AGENT) == 0u)
            __builtin_amdgcn_s_sleep(1);
    }
    __syncthreads();
}

// ---------------------------------------------------------------------------
// Zx chunk GEMM: M=4096 (B*CCH), N=4096, K=1024 (x-part). Output GATE-PACKED:
// Zxc[(b*CCH+tc)*4096 + j*4 + gate]   (R12-proven, unchanged)
// ---------------------------------------------------------------------------
__global__ __launch_bounds__(256) void zx_gemm(
    const float* __restrict__ X, const unsigned short* __restrict__ Wr,
    const float* __restrict__ bre, float* __restrict__ Zxc, int t0)
{
    __shared__ __align__(16) unsigned short ALds[2][128 * 64];
    __shared__ __align__(16) unsigned short BLds[2][128 * 64];

    const int tid = threadIdx.x, lane = tid & 63, wv = tid >> 6;
    const int wr = wv >> 1, wc = wv & 1;
    const int m0 = (blockIdx.x >> 5) * 128, n0 = (blockIdx.x & 31) * 128;

    f32x4 acc[4][4];
#pragma unroll
    for (int i = 0; i < 4; ++i)
#pragma unroll
        for (int jn = 0; jn < 4; ++jn) acc[i][jn] = 0.f;

    auto stage = [&](int buf, int ki) {
        const int k0 = ki * 64;
#pragma unroll
        for (int i = 0; i < 4; ++i) {
            int slot = i * 256 + tid;
            int r = slot >> 3, cp = slot & 7;
            int c = cp ^ (r & 7);
            int m = m0 + r, b = m >> 5, tc = m & 31;
            const float* src = X + ((size_t)b * Tt + t0 + tc) * Dd + k0 + c * 8;
            *reinterpret_cast<s16x8*>(&ALds[buf][slot * 8]) = cvt8(src);
        }
#pragma unroll
        for (int i = 0; i < 4; ++i) {
            int slot = i * 256 + tid;
            int r = slot >> 3, cp = slot & 7;
            int c = cp ^ (r & 7);
            const unsigned short* src = Wr + (size_t)(n0 + r) * KD + k0 + c * 8;
            __builtin_amdgcn_global_load_lds((gcvoid*)src,
                (lvoid*)&BLds[buf][(i * 256 + wv * 64) * 8], 16, 0, 0);
        }
    };

    auto compute = [&](int buf) {
#pragma unroll
        for (int ks = 0; ks < 2; ++ks) {
            int ck = ks * 4 + (lane >> 4);
            s16x8 af[4], bf8[4];
#pragma unroll
            for (int m = 0; m < 4; ++m) {
                int ra = wr * 64 + m * 16 + (lane & 15);
                af[m] = *reinterpret_cast<const s16x8*>(&ALds[buf][ra * 64 + (ck ^ (ra & 7)) * 8]);
            }
#pragma unroll
            for (int n = 0; n < 4; ++n) {
                int rb = wc * 64 + n * 16 + (lane & 15);
                bf8[n] = *reinterpret_cast<const s16x8*>(&BLds[buf][rb * 64 + (ck ^ (rb & 7)) * 8]);
            }
#pragma unroll
            for (int m = 0; m < 4; ++m)
#pragma unroll
                for (int n = 0; n < 4; ++n)
                    acc[m][n] = __builtin_amdgcn_mfma_f32_16x16x32_bf16(af[m], bf8[n], acc[m][n], 0, 0, 0);
        }
    };

    stage(0, 0);
#pragma unroll 1
    for (int ki = 0; ki < 16; ++ki) {
        __syncthreads();   // compiler emits vmcnt(0)+lgkmcnt(0) drain here
        if (ki + 1 < 16) stage((ki + 1) & 1, ki + 1);
        compute(ki & 1);
    }

#pragma unroll
    for (int ni = 0; ni < 4; ++ni) {
        int gcol = n0 + wc * 64 + ni * 16 + (lane & 15);
        float bias = bre[gcol];
        int gg = gcol >> 5, nn = gcol & 31;
        int zcol = gg * 32 + (nn & 7) * 4 + (nn >> 3);
#pragma unroll
        for (int mi = 0; mi < 4; ++mi) {
            int rbase = m0 + wr * 64 + mi * 16 + (lane >> 4) * 4;
#pragma unroll
            for (int r = 0; r < 4; ++r)
                Zxc[(size_t)(rbase + r) * 4096 + zcol] = acc[mi][ni][r] + bias;
        }
    }
}

// ---------------------------------------------------------------------------
// Persistent per-chunk recurrent kernel (R12 base). 256 blocks = 128 col-
// groups x 2 mh. Wh (64 KB) in LDS once; c in registers; h ring (depth 32):
// writes sc1, reads plain cached (fresh slot per step). NEW vs R12: epilogue
// ordered [zx-prefetch][h-stores][out-stores] + split-drain vmcnt(4) so the
// out-stores' cold-line RFOs stay off the barrier's critical path.
// ---------------------------------------------------------------------------
__global__ __launch_bounds__(256) void lstm_chunk(
    const unsigned short* __restrict__ Wr,
    const float* __restrict__ Zxc,
    unsigned short* __restrict__ hring,   // CCH slots of [Bb][Hh] bf16
    float* __restrict__ cbuf,
    float* __restrict__ out,
    unsigned* __restrict__ cntA,
    unsigned* __restrict__ cntB,
    unsigned* __restrict__ flag,
    int t0)
{
    __shared__ __align__(16) unsigned short Bl[32 * 1024];   // 64 KB Wh slice

    const int tid = threadIdx.x, lane = tid & 63, w = tid >> 6;
    const int bid = blockIdx.x;
    const int g = bid >> 1, mh = bid & 1;

    // Stage Wh slice once (linear LDS dest, XOR-swizzled global source).
#pragma unroll
    for (int i = 0; i < 16; ++i) {
        int q = (w * 16 + i) * 64 + lane;
        int n = q >> 7, cp = q & 127;
        int cs = (cp & ~7) | ((cp ^ n) & 7);
        const unsigned short* src = Wr + (size_t)(g * 32 + n) * KD + Dd + cs * 8;
        __builtin_amdgcn_global_load_lds((gcvoid*)src,
            (lvoid*)&Bl[(w * 16 + i) * 512], 16, 0, 0);
    }
    asm volatile("s_waitcnt vmcnt(0)" ::: "memory");
    __syncthreads();

    const int nlo = lane & 15;
    const int r0 = mh * 64 + w * 16 + nlo;
    const unsigned short* b0p = &Bl[nlo * 1024];
    const int jj = lane & 7, j = g * 8 + jj;
    const bool hi = (lane & 8) != 0;
    const int rowb = mh * 64 + w * 16 + (lane >> 4) * 4;

    f32x4 creg;
#pragma unroll
    for (int r = 0; r < 4; ++r)
        creg[r] = cbuf[(size_t)(rowb + r) * Hh + j];

    f32x4 zx[4];
#pragma unroll
    for (int r = 0; r < 4; ++r)
        zx[r] = *reinterpret_cast<const f32x4*>(
            Zxc + ((size_t)(rowb + r) * CCH + 0) * 4096 + j * 4);

#pragma unroll 1
    for (int tt = 0; tt < CCH; ++tt) {
        const int t = t0 + tt;
        const unsigned short* hin = hring + (size_t)(t & (CCH - 1)) * (Bb * Hh);
        unsigned short* houtp = hring + (size_t)((t + 1) & (CCH - 1)) * (Bb * Hh);
        const unsigned short* arow = hin + (size_t)r0 * Hh + (lane >> 4) * 8;

        // A-operand: plain cached loads (first touch per XCD misses to LLC,
        // the rest are L2 hits). R8/R12-proven read structure.
        s16x8 af[32];
#pragma unroll
        for (int ki = 0; ki < 32; ++ki)
            af[ki] = *reinterpret_cast<const s16x8*>(arow + ki * 32);

        f32x4 acc0 = 0.f, acc1 = 0.f;
#pragma unroll
        for (int ki = 0; ki < 32; ++ki) {
            int ck = ki * 4 + (lane >> 4);
            int p = (ck & ~7) | ((ck ^ nlo) & 7);
            s16x8 b0 = *reinterpret_cast<const s16x8*>(b0p + p * 8);
            s16x8 b1 = *reinterpret_cast<const s16x8*>(b0p + 16 * 1024 + p * 8);
            acc0 = __builtin_amdgcn_mfma_f32_16x16x32_bf16(af[ki], b0, acc0, 0, 0, 0);
            acc1 = __builtin_amdgcn_mfma_f32_16x16x32_bf16(af[ki], b1, acc1, 0, 0, 0);
        }

        f32x4 y0, y1;
#pragma unroll
        for (int r = 0; r < 4; ++r) {
            y0[r] = __shfl_xor(acc0[r], 8, 64);
            y1[r] = __shfl_xor(acc1[r], 8, 64);
        }

        // (1) prefetch next step's Zx — issued first, drained by vmcnt(4)
        f32x4 zxn[4];
        if (tt + 1 < CCH) {
#pragma unroll
            for (int r = 0; r < 4; ++r)
                zxn[r] = *reinterpret_cast<const f32x4*>(
                    Zxc + ((size_t)(rowb + r) * CCH + (tt + 1)) * 4096 + j * 4);
        }

        // gate math -> hn values in registers
        float hnv[4];
#pragma unroll
        for (int r = 0; r < 4; ++r) {
            float vf = hi ? y0[r] : acc0[r];
            float vi = hi ? acc0[r] : y0[r];
            float vo = hi ? y1[r] : acc1[r];
            float vg = hi ? acc1[r] : y1[r];
            float zf = vf + zx[r][0], zi = vi + zx[r][1];
            float zo = vo + zx[r][2], zc = vg + zx[r][3];
            float fg = sigf(zf), ig = sigf(zi), og = sigf(zo), gv = tanhfast(zc);
            float cnew = fg * creg[r] + ig * gv;
            creg[r] = cnew;
            hnv[r] = og * tanhfast(cnew);
        }

        // (2) h-stores (sc1, the handoff) — all four issued before any out-store;
        // asm memory clobbers pin the order.
        if (!hi) {
#pragma unroll
            for (int r = 0; r < 4; ++r)
                cstore2(houtp + (size_t)(rowb + r) * Hh + j, (unsigned)f2bf(hnv[r]));
        }
        // (3) out-stores (plain cached, cold-line RFOs) — left in flight.
        if (!hi) {
#pragma unroll
            for (int r = 0; r < 4; ++r)
                out[((size_t)(rowb + r) * Tt + (Tt - 1 - t)) * Hh + j] = hnv[r];
        }
#pragma unroll
        for (int r = 0; r < 4; ++r) zx[r] = zxn[r];

        if (tt + 1 < CCH) {
            // split-drain: zxn loads + h-stores complete; <=4 newest (out) in flight
            asm volatile("s_waitcnt vmcnt(4)" ::: "memory");
            __builtin_amdgcn_sched_barrier(0);
            gbar(cntA, cntB, flag, t, bid);
        }
    }

    if (!hi) {
#pragma unroll
        for (int r = 0; r < 4; ++r)
            cbuf[(size_t)(rowb + r) * Hh + j] = creg[r];
    }
}

// ---------------------------------------------------------------------------
// Weight reorg as LDS-tiled transpose: Wr[n][k] = bf16(Wg[k][col(n)]),
// n = (col>>3)*32 + gate*8 + (col&7).
// ---------------------------------------------------------------------------
__global__ __launch_bounds__(256) void conv_w(
    const float* __restrict__ Wf, const float* __restrict__ Wi,
    const float* __restrict__ Wo, const float* __restrict__ Wc,
    unsigned short* __restrict__ Wr)
{
    __shared__ float sm[64 * 65];
    const int tid = threadIdx.x;
    const int bid = blockIdx.x;
    const int gate = bid & 3;
    const int rest = bid >> 2;
    const int k0 = (rest & 31) * 64;
    const int c0 = (rest >> 5) * 64;
    const float* Wg = (gate == 0) ? Wf : (gate == 1) ? Wi : (gate == 2) ? Wo : Wc;

#pragma unroll
    for (int it = 0; it < 16; ++it) {
        int kl = it * 4 + (tid >> 6), cl = tid & 63;
        sm[kl * 65 + cl] = Wg[(size_t)(k0 + kl) * Hh + c0 + cl];
    }
    __syncthreads();
#pragma unroll
    for (int it = 0; it < 16; ++it) {
        int nl = it * 4 + (tid >> 6), kl = tid & 63;
        int col = c0 + nl;
        int n = (col >> 3) * 32 + gate * 8 + (col & 7);
        Wr[(size_t)n * KD + k0 + kl] = f2bf(sm[kl * 65 + nl]);
    }
}

#define NBAR_U32 (512 * 8 * 32 + 512 * 32 + 512)

__global__ void init_all(unsigned short* __restrict__ hring, float* __restrict__ cbuf,
                         unsigned* __restrict__ bars, float* __restrict__ bre,
                         const float* __restrict__ bF, const float* __restrict__ bI,
                         const float* __restrict__ bO, const float* __restrict__ bC) {
    int i = blockIdx.x * 256 + threadIdx.x;
    if (i < 2 * Bb * Hh) hring[i] = 0;   // slots 0 (t=0 carry) and 1 (fallback)
    if (i < Bb * Hh) cbuf[i] = 0.f;
    if (i < NBAR_U32) bars[i] = 0u;
    if (i < 4096) {
        int gate = (i >> 3) & 3, g = i >> 5, jjv = i & 7;
        int col = g * 8 + jjv;
        const float* bg = (gate == 0) ? bF : (gate == 1) ? bI : (gate == 2) ? bO : bC;
        bre[i] = bg[col];
    }
}

// ---------------------------------------------------------------------------
// Fallback path: one fused kernel per time step, K=2048 (round-1/3 proven).
// ---------------------------------------------------------------------------
__global__ __launch_bounds__(256) void lstm_step(
    const float* __restrict__ X, const unsigned short* __restrict__ Wr,
    const float* __restrict__ bre,
    const unsigned short* __restrict__ hin, unsigned short* __restrict__ hout,
    float* __restrict__ cbuf, float* __restrict__ out, int t)
{
    __shared__ __align__(16) unsigned short Alds[2][64 * 64];
    __shared__ __align__(16) unsigned short Blds[2][32 * 64];
    __shared__ float zlds[64 * 33];

    const int tid = threadIdx.x, lane = tid & 63, w = tid >> 6;
    const int g = blockIdx.x >> 1, mh = blockIdx.x & 1;

    f32x4 acc[2];
    acc[0] = 0.f; acc[1] = 0.f;

    auto stageA = [&](int buf, int ki) {
        const int k0 = ki * 64;
#pragma unroll
        for (int i = 0; i < 2; ++i) {
            int slot = tid + 256 * i;
            int r = slot >> 3, cp = slot & 7;
            int c = cp ^ (r & 7);
            int k = k0 + c * 8;
            s16x8 v;
            if (k < Dd) {
                v = cvt8(X + ((size_t)(mh * 64 + r) * Tt + t) * Dd + k);
            } else {
                v = *reinterpret_cast<const s16x8*>(hin + (size_t)(mh * 64 + r) * Hh + (k - Dd));
            }
            *reinterpret_cast<s16x8*>(&Alds[buf][slot * 8]) = v;
        }
    };
    auto stageB = [&](int buf, int ki) {
        int n = tid >> 3, cp = tid & 7;
        int c = cp ^ (n & 7);
        const unsigned short* src = Wr + (size_t)(g * 32 + n) * KD + ki * 64 + c * 8;
        *reinterpret_cast<s16x8*>(&Blds[buf][tid * 8]) = *reinterpret_cast<const s16x8*>(src);
    };
    auto compute = [&](int buf) {
#pragma unroll
        for (int ks = 0; ks < 2; ++ks) {
            int ra = w * 16 + (lane & 15);
            int cha = (ks * 4 + (lane >> 4)) ^ (ra & 7);
            s16x8 af = *reinterpret_cast<const s16x8*>(&Alds[buf][ra * 64 + cha * 8]);
#pragma unroll
            for (int nt = 0; nt < 2; ++nt) {
                int n = nt * 16 + (lane & 15);
                int chb = (ks * 4 + (lane >> 4)) ^ (n & 7);
                s16x8 bf8 = *reinterpret_cast<const s16x8*>(&Blds[buf][n * 64 + chb * 8]);
                acc[nt] = __builtin_amdgcn_mfma_f32_16x16x32_bf16(af, bf8, acc[nt], 0, 0, 0);
            }
        }
    };

    stageA(0, 0); stageB(0, 0);
#pragma unroll 1
    for (int ki = 0; ki < 32; ++ki) {
        __syncthreads();
        if (ki + 1 < 32) { stageA((ki + 1) & 1, ki + 1); stageB((ki + 1) & 1, ki + 1); }
        compute(ki & 1);
    }

    {
        int rbase = w * 16 + (lane >> 4) * 4;
#pragma unroll
        for (int nt = 0; nt < 2; ++nt) {
            int col = nt * 16 + (lane & 15);
#pragma unroll
            for (int r = 0; r < 4; ++r)
                zlds[(rbase + r) * 33 + col] = acc[nt][r];
        }
    }
    __syncthreads();

#pragma unroll
    for (int it = 0; it < 2; ++it) {
        int idx = tid + it * 256;
        int row = idx >> 3, jj = idx & 7;
        int jx = g * 8 + jj;
        int grow = mh * 64 + row;
        float zf = zlds[row * 33 + jj]      + bre[g * 32 + jj];
        float zi = zlds[row * 33 + 8 + jj]  + bre[g * 32 + 8 + jj];
        float zo = zlds[row * 33 + 16 + jj] + bre[g * 32 + 16 + jj];
        float zc = zlds[row * 33 + 24 + jj] + bre[g * 32 + 24 + jj];
        float fg = sigf(zf), ig = sigf(zi), og = sigf(zo), gv = tanhfast(zc);
        float cold = cbuf[(size_t)grow * Hh + jx];
        float cnew = fg * cold + ig * gv;
        cbuf[(size_t)grow * Hh + jx] = cnew;
        float hn = og * tanhfast(cnew);
        hout[(size_t)grow * Hh + jx] = f2bf(hn);
        out[((size_t)grow * Tt + (Tt - 1 - t)) * Hh + jx] = hn;
    }
}

extern "C" void kernel_launch(void* const* d_in, const int* in_sizes, int n_in,
                              void* d_out, int out_size, void* d_ws, size_t ws_size,
                              hipStream_t stream) {
    (void)in_sizes; (void)n_in; (void)out_size;
    const float* X  = (const float*)d_in[0];
    const float* Wf = (const float*)d_in[1];
    const float* bF = (const float*)d_in[2];
    const float* Wi = (const float*)d_in[3];
    const float* bI = (const float*)d_in[4];
    const float* Wo = (const float*)d_in[5];
    const float* bO = (const float*)d_in[6];
    const float* Wc = (const float*)d_in[7];
    const float* bC = (const float*)d_in[8];
    float* out = (float*)d_out;

    char* ws = (char*)d_ws;
    size_t off = 0;
    auto carve = [&](size_t sz) { char* p = ws + off; off = (off + sz + 255) & ~(size_t)255; return p; };
    unsigned short* Wr    = (unsigned short*)carve((size_t)4096 * KD * 2);        // 16 MB
    float*          bre   = (float*)carve(4096 * 4);
    unsigned short* hring = (unsigned short*)carve((size_t)CCH * Bb * Hh * 2);    // 8 MB
    float*          cbuf  = (float*)carve((size_t)Bb * Hh * 4);
    unsigned*       bars  = (unsigned*)carve((size_t)NBAR_U32 * 4);               // ~0.6 MB
    float*          Zxc   = (float*)carve((size_t)4096 * 4096 * 4);               // 64 MB
    const size_t need = off;

    unsigned* cntA = bars;
    unsigned* cntB = bars + 512 * 8 * 32;
    unsigned* flag = bars + 512 * 8 * 32 + 512 * 32;

    conv_w<<<2048, 256, 0, stream>>>(Wf, Wi, Wo, Wc, Wr);
    init_all<<<1024, 256, 0, stream>>>(hring, cbuf, bars, bre, bF, bI, bO, bC);

    int t_resume = 0;                 // first timestep NOT handled by coop path
    if (ws_size >= need) {
        const unsigned short* Wr_c = Wr;
        const float* Zxc_c = Zxc;
        for (int c = 0; c < NCHUNK; ++c) {
            int t0 = c * CCH;
            zx_gemm<<<1024, 256, 0, stream>>>(X, Wr, bre, Zxc, t0);
            void* args[] = {(void*)&Wr_c, (void*)&Zxc_c, (void*)&hring, (void*)&cbuf,
                            (void*)&out, (void*)&cntA, (void*)&cntB, (void*)&flag, (void*)&t0};
            hipError_t rc = hipLaunchCooperativeKernel((void*)lstm_chunk, dim3(NBLK),
                                                       dim3(256), args, 0, stream);
            if (rc != hipSuccess) break;     // coop launch rejected: resume per-step
            t_resume = t0 + CCH;
        }
    }

    // Per-step proven path for anything the coop path didn't cover.
    // (h state at t_resume sits in ring slot 0 == slot (t_resume & 1).)
    for (int t = t_resume; t < Tt; ++t) {
        const unsigned short* hin = hring + (size_t)(t & 1) * Bb * Hh;
        unsigned short*      houtp = hring + (size_t)((t + 1) & 1) * Bb * Hh;
        lstm_step<<<256, 256, 0, stream>>>(X, Wr, bre, hin, houtp, cbuf, out, t);
    }
}